// Round 1
// baseline (1812.351 us; speedup 1.0000x reference)
//
#include <hip/hip_runtime.h>
#include <math.h>

#define BB 4
#define LQ 2048
#define LK 2048
#define DK 512
#define DV 512
#define NEG_SLOPE 0.01f
#define RPB 8   // q-rows per block in attention kernel

// ---------------------------------------------------------------------------
// Kernel A: one wave (64 lanes) per row. Computes dot(row, w) for all q rows
// (B*LQ of them) then all k rows (B*LK). Results into ws:
//   ws[0 .. B*LQ)             = qw[b][q]
//   ws[B*LQ .. B*LQ + B*LK)   = kw[b][k]
// ---------------------------------------------------------------------------
__global__ __launch_bounds__(256) void qkw_kernel(const float* __restrict__ q,
                                                  const float* __restrict__ k,
                                                  const float* __restrict__ w,
                                                  float* __restrict__ ws) {
    int gw   = (int)((blockIdx.x * blockDim.x + threadIdx.x) >> 6);  // global wave id
    int lane = threadIdx.x & 63;
    const int nq = BB * LQ;
    const float* row;
    if (gw < nq) row = q + (size_t)gw * DK;
    else         row = k + (size_t)(gw - nq) * DK;

    float acc = 0.f;
#pragma unroll
    for (int j = 0; j < DK; j += 256) {
        int idx = j + lane * 4;
        float4 rv = *reinterpret_cast<const float4*>(row + idx);
        float4 wv = *reinterpret_cast<const float4*>(w + idx);
        acc += rv.x * wv.x + rv.y * wv.y + rv.z * wv.z + rv.w * wv.w;
    }
#pragma unroll
    for (int off = 32; off >= 1; off >>= 1) acc += __shfl_xor(acc, off, 64);
    if (lane == 0) ws[gw] = acc;
}

// ---------------------------------------------------------------------------
// Kernel B: one block = (batch b, 8 consecutive q rows). 256 threads (4 waves).
// Phase 1 (per wave, 2 rows each): scores -> masked -> softmax (3 passes over
//   the row held in LDS), write normalized attn to global, keep p in LDS.
// Phase 2: PV matmul. thread t handles row (t>>5), cols [(t&31)*16, +16).
// ---------------------------------------------------------------------------
__global__ __launch_bounds__(256, 2) void attn_kernel(
        const float* __restrict__ v,
        const int*   __restrict__ mask,
        const float* __restrict__ ws,
        float* __restrict__ out,
        float* __restrict__ attn_out) {
    __shared__ float p[RPB][LK];   // 64 KB

    const int b    = blockIdx.y;
    const int q0   = blockIdx.x * RPB;
    const int wave = threadIdx.x >> 6;
    const int lane = threadIdx.x & 63;

    const float* qw = ws;                          // [B*LQ]
    const float* kw = ws + BB * LQ + b * LK;       // this batch's kw[LK]

    // ---- softmax phase: each wave owns RPB/4 = 2 rows ----
#pragma unroll
    for (int rr = 0; rr < RPB / 4; ++rr) {
        const int r  = wave * (RPB / 4) + rr;
        const int qi = q0 + r;
        const float qwv = qw[b * LQ + qi];
        const int* mrow = mask + ((size_t)(b * LQ + qi)) * LK;

        // pass 1: scores + mask, track running max
        float m = -INFINITY;
        for (int kk = lane; kk < LK; kk += 64) {
            float s = qwv - kw[kk];
            s = (s >= 0.f) ? s : NEG_SLOPE * s;
            s = mrow[kk] ? s : -INFINITY;
            p[r][kk] = s;
            m = fmaxf(m, s);
        }
#pragma unroll
        for (int off = 32; off >= 1; off >>= 1)
            m = fmaxf(m, __shfl_xor(m, off, 64));

        // pass 2: exp + sum
        float sum = 0.f;
        for (int kk = lane; kk < LK; kk += 64) {
            float s = p[r][kk];
            float e = (s == -INFINITY) ? 0.f : __expf(s - m);
            p[r][kk] = e;
            sum += e;
        }
#pragma unroll
        for (int off = 32; off >= 1; off >>= 1)
            sum += __shfl_xor(sum, off, 64);
        const float inv = (sum > 0.f) ? 1.f / sum : 0.f;

        // pass 3: normalize, write attn output, keep p in LDS
        float* arow = attn_out + ((size_t)(b * LQ + qi)) * LK;
        for (int kk = lane; kk < LK; kk += 64) {
            float val = p[r][kk] * inv;
            p[r][kk] = val;
            arow[kk] = val;
        }
    }
    __syncthreads();

    // ---- PV phase ----
    const int r     = threadIdx.x >> 5;        // 0..7
    const int cbase = (threadIdx.x & 31) * 16; // 0..496
    float4 acc[4];
#pragma unroll
    for (int j = 0; j < 4; ++j) acc[j] = make_float4(0.f, 0.f, 0.f, 0.f);

    const float* vbase = v + (size_t)b * LK * DV + cbase;
#pragma unroll 4
    for (int kk = 0; kk < LK; ++kk) {
        const float pv = p[r][kk];
        const float4* v4 = reinterpret_cast<const float4*>(vbase + (size_t)kk * DV);
#pragma unroll
        for (int j = 0; j < 4; ++j) {
            float4 t = v4[j];
            acc[j].x += pv * t.x;
            acc[j].y += pv * t.y;
            acc[j].z += pv * t.z;
            acc[j].w += pv * t.w;
        }
    }

    float* orow = out + ((size_t)(b * LQ + q0 + r)) * DV + cbase;
#pragma unroll
    for (int j = 0; j < 4; ++j)
        reinterpret_cast<float4*>(orow)[j] = acc[j];
}

// ---------------------------------------------------------------------------
extern "C" void kernel_launch(void* const* d_in, const int* in_sizes, int n_in,
                              void* d_out, int out_size, void* d_ws, size_t ws_size,
                              hipStream_t stream) {
    const float* q    = (const float*)d_in[0];
    const float* k    = (const float*)d_in[1];
    const float* v    = (const float*)d_in[2];
    const int*   mask = (const int*)d_in[3];
    const float* w    = (const float*)d_in[4];

    float* out  = (float*)d_out;                        // [B, LQ, DV]
    float* attn = out + (size_t)BB * LQ * DV;           // [B, LQ, LK]
    float* ws   = (float*)d_ws;                         // 64 KB used

    // A: qw/kw — B*(LQ+LK) = 16384 waves, 4 waves/block -> 4096 blocks
    qkw_kernel<<<4096, 256, 0, stream>>>(q, k, w, ws);

    // B: attention — one block per (8 q-rows, batch)
    dim3 grid(LQ / RPB, BB);
    attn_kernel<<<grid, 256, 0, stream>>>(v, mask, ws, out, attn);
}

// Round 2
// 231.221 us; speedup vs baseline: 7.8382x; 7.8382x over previous
//
#include <hip/hip_runtime.h>
#include <math.h>

#define BB 4
#define LQ 2048
#define LK 2048
#define DK 512
#define DV 512

typedef __attribute__((ext_vector_type(8))) short bf16x8;
typedef __attribute__((ext_vector_type(4))) float f32x4;

// ws layout (f32-element offsets for the float region; vH/vL are u16 arrays after)
#define WS_QW  0                       // f32[B*LQ]
#define WS_KW  (BB*LQ)                 // f32[B*LK]
#define WS_M   (WS_KW + BB*LK)         // f32[B*LQ]
#define WS_INV (WS_M + BB*LQ)          // f32[B*LQ]
#define WS_V16 (WS_INV + BB*LQ)        // then: vH u16[B*DV*LK], vL u16[B*DV*LK]

__device__ inline void bsplit(float f, unsigned short& h, unsigned short& l) {
    unsigned int u  = __float_as_uint(f);
    unsigned int hu = u & 0xFFFF0000u;
    float rest = f - __uint_as_float(hu);
    h = (unsigned short)(u >> 16);
    l = (unsigned short)(__float_as_uint(rest) >> 16);
}

__device__ inline unsigned int packsplit(float f) {
    unsigned int u  = __float_as_uint(f);
    unsigned int hu = u & 0xFFFF0000u;
    float rest = f - __uint_as_float(hu);
    return hu | (__float_as_uint(rest) >> 16);
}

// ---------------------------------------------------------------------------
// A: qw/kw — one wave per row.
// ---------------------------------------------------------------------------
__global__ __launch_bounds__(256) void qkw_kernel(const float* __restrict__ q,
                                                  const float* __restrict__ k,
                                                  const float* __restrict__ w,
                                                  float* __restrict__ ws) {
    int gw   = (int)((blockIdx.x * blockDim.x + threadIdx.x) >> 6);
    int lane = threadIdx.x & 63;
    const int nq = BB * LQ;
    const float* row = (gw < nq) ? (q + (size_t)gw * DK) : (k + (size_t)(gw - nq) * DK);

    float acc = 0.f;
#pragma unroll
    for (int j = 0; j < DK; j += 256) {
        int idx = j + lane * 4;
        float4 rv = *reinterpret_cast<const float4*>(row + idx);
        float4 wv = *reinterpret_cast<const float4*>(w + idx);
        acc += rv.x * wv.x + rv.y * wv.y + rv.z * wv.z + rv.w * wv.w;
    }
#pragma unroll
    for (int off = 32; off >= 1; off >>= 1) acc += __shfl_xor(acc, off, 64);
    if (lane == 0) ws[gw] = acc;
}

// ---------------------------------------------------------------------------
// C: v -> vT split bf16 (hi/lo), transposed to [b][n][k] via LDS 64x64 tile.
// ---------------------------------------------------------------------------
__global__ __launch_bounds__(256) void vpack_kernel(const float* __restrict__ v,
                                                    unsigned short* __restrict__ vH,
                                                    unsigned short* __restrict__ vL) {
    __shared__ unsigned int tile[64][65];
    const int b  = blockIdx.z;
    const int n0 = blockIdx.y * 64;
    const int k0 = blockIdx.x * 64;
    const int t  = threadIdx.x;
    const int tr = t >> 4, tc = t & 15;

#pragma unroll
    for (int p = 0; p < 4; ++p) {
        int kk = k0 + p * 16 + tr;
        float4 f = *reinterpret_cast<const float4*>(v + ((size_t)(b * LK + kk)) * DV + n0 + tc * 4);
        tile[p * 16 + tr][tc * 4 + 0] = packsplit(f.x);
        tile[p * 16 + tr][tc * 4 + 1] = packsplit(f.y);
        tile[p * 16 + tr][tc * 4 + 2] = packsplit(f.z);
        tile[p * 16 + tr][tc * 4 + 3] = packsplit(f.w);
    }
    __syncthreads();

#pragma unroll
    for (int p = 0; p < 4; ++p) {
        int nn = n0 + p * 16 + tr;
        int kc = tc * 4;
        unsigned int w0 = tile[kc + 0][p * 16 + tr];
        unsigned int w1 = tile[kc + 1][p * 16 + tr];
        unsigned int w2 = tile[kc + 2][p * 16 + tr];
        unsigned int w3 = tile[kc + 3][p * 16 + tr];
        uint2 hi, lo;
        hi.x = (w0 >> 16) | (w1 & 0xFFFF0000u);
        hi.y = (w2 >> 16) | (w3 & 0xFFFF0000u);
        lo.x = (w0 & 0xFFFFu) | (w1 << 16);
        lo.y = (w2 & 0xFFFFu) | (w3 << 16);
        size_t off = ((size_t)(b * DV + nn)) * LK + k0 + kc;
        *reinterpret_cast<uint2*>(vH + off) = hi;
        *reinterpret_cast<uint2*>(vL + off) = lo;
    }
}

// ---------------------------------------------------------------------------
// B1: per-row masked online softmax stats (m, 1/sum). One wave per row.
// ---------------------------------------------------------------------------
__global__ __launch_bounds__(256) void rowstat_kernel(const int* __restrict__ mask,
                                                      float* __restrict__ ws) {
    __shared__ float kws[LK];
    const int b = (blockIdx.x * 4) / LQ;
    const int t = threadIdx.x;

    const float4* kw4 = reinterpret_cast<const float4*>(ws + WS_KW + b * LK);
#pragma unroll
    for (int i = 0; i < 2; ++i)
        reinterpret_cast<float4*>(kws)[t + i * 256] = kw4[t + i * 256];
    __syncthreads();

    const int wave = t >> 6, lane = t & 63;
    const int rid  = blockIdx.x * 4 + wave;
    const float qwv = ws[WS_QW + rid];
    const int* mrow = mask + (size_t)rid * LK;

    float m = -INFINITY, s = 0.f;
#pragma unroll
    for (int i = 0; i < 8; ++i) {
        int e = (i * 64 + lane) * 4;
        int4  mi = *reinterpret_cast<const int4*>(mrow + e);
        float4 kv = reinterpret_cast<const float4*>(kws)[i * 64 + lane];
        float vals[4] = {kv.x, kv.y, kv.z, kv.w};
        int   msks[4] = {mi.x, mi.y, mi.z, mi.w};
#pragma unroll
        for (int j = 0; j < 4; ++j) {
            float sc = qwv - vals[j];
            sc = fmaxf(sc, 0.01f * sc);
            if (msks[j]) {
                if (sc > m) { s = s * __expf(m - sc) + 1.f; m = sc; }
                else        { s += __expf(sc - m); }
            }
        }
    }
#pragma unroll
    for (int off = 32; off >= 1; off >>= 1) {
        float mo = __shfl_xor(m, off, 64);
        float so = __shfl_xor(s, off, 64);
        float M  = fmaxf(m, mo);
        float sa = (m  == M) ? s  : s  * __expf(m  - M);
        float sb = (mo == M) ? so : so * __expf(mo - M);
        m = M; s = sa + sb;
    }
    if (lane == 0) {
        ws[WS_M   + rid] = m;
        ws[WS_INV + rid] = (s > 0.f) ? 1.f / s : 0.f;
    }
}

// ---------------------------------------------------------------------------
// B2: fused p-compute + attn write + split-bf16 MFMA PV.
// Block = 256 thr (4 waves), 32 q-rows, k-chunks of 32. Waves split N (128 each).
// ---------------------------------------------------------------------------
__global__ __launch_bounds__(256) void pv_kernel(const int* __restrict__ mask,
                                                 const float* __restrict__ ws,
                                                 const unsigned short* __restrict__ vH,
                                                 const unsigned short* __restrict__ vL,
                                                 float* __restrict__ out,
                                                 float* __restrict__ attn) {
    __shared__ unsigned short pH[32 * 40];   // bf16 hi, pitch 40 (80B rows)
    __shared__ unsigned short pL[32 * 40];   // bf16 lo

    const int wg = blockIdx.x;               // XCD-swizzled decode: same b on same XCD pair
    const int b  = (wg >> 1) & 3;
    const int qt = ((wg >> 3) << 1) | (wg & 1);
    const int q0 = qt * 32;

    const int t = threadIdx.x;
    const int w = t >> 6, l = t & 63;
    const int tq = t >> 3, tk = t & 7;

    const int rid = b * LQ + q0 + tq;
    const float qv = ws[WS_QW + rid];
    const float mv = ws[WS_M + rid];
    const float iv = ws[WS_INV + rid];
    const float* kwrow = ws + WS_KW + b * LK;
    const int*   mrow  = mask + (size_t)rid * LK;
    float*       arow  = attn + (size_t)rid * LK;
    const unsigned short* vHb = vH + (size_t)b * DV * LK;
    const unsigned short* vLb = vL + (size_t)b * DV * LK;

    f32x4 acc[2][8];
#pragma unroll
    for (int mf = 0; mf < 2; ++mf)
#pragma unroll
        for (int nb = 0; nb < 8; ++nb)
            acc[mf][nb] = (f32x4){0.f, 0.f, 0.f, 0.f};

    int4 mi = *reinterpret_cast<const int4*>(mrow + tk * 4);

    for (int c = 0; c < 64; ++c) {
        const int k0 = c * 32;
        // ---- p-compute phase (all 256 threads; rows tq, k tk*4..+4) ----
        float4 kv = *reinterpret_cast<const float4*>(kwrow + k0 + tk * 4);
        float kvs[4] = {kv.x, kv.y, kv.z, kv.w};
        int   ms [4] = {mi.x, mi.y, mi.z, mi.w};
        float p[4];
        ushort4 h4, l4;
        unsigned short hh, ll;
#pragma unroll
        for (int j = 0; j < 4; ++j) {
            float sc = qv - kvs[j];
            sc = fmaxf(sc, 0.01f * sc);
            p[j] = ms[j] ? __expf(sc - mv) * iv : 0.f;
        }
        *reinterpret_cast<float4*>(arow + k0 + tk * 4) = make_float4(p[0], p[1], p[2], p[3]);
        bsplit(p[0], hh, ll); h4.x = hh; l4.x = ll;
        bsplit(p[1], hh, ll); h4.y = hh; l4.y = ll;
        bsplit(p[2], hh, ll); h4.z = hh; l4.z = ll;
        bsplit(p[3], hh, ll); h4.w = hh; l4.w = ll;
        *reinterpret_cast<ushort4*>(&pH[tq * 40 + tk * 4]) = h4;
        *reinterpret_cast<ushort4*>(&pL[tq * 40 + tk * 4]) = l4;
        if (c < 63) mi = *reinterpret_cast<const int4*>(mrow + k0 + 32 + tk * 4);
        __syncthreads();

        // ---- MFMA phase (per wave: n in [w*128, w*128+128)) ----
        bf16x8 aH[2], aL[2];
#pragma unroll
        for (int mf = 0; mf < 2; ++mf) {
            int ar = (mf * 16 + (l & 15)) * 40 + 8 * (l >> 4);
            aH[mf] = *reinterpret_cast<const bf16x8*>(&pH[ar]);
            aL[mf] = *reinterpret_cast<const bf16x8*>(&pL[ar]);
        }
        const size_t koff = (size_t)k0 + 8 * (l >> 4);
        const int nbase = w * 128 + (l & 15);
#pragma unroll
        for (int nb = 0; nb < 8; ++nb) {
            size_t off = (size_t)(nbase + nb * 16) * LK + koff;
            bf16x8 bh = *reinterpret_cast<const bf16x8*>(vHb + off);
            bf16x8 bl = *reinterpret_cast<const bf16x8*>(vLb + off);
#pragma unroll
            for (int mf = 0; mf < 2; ++mf) {
                acc[mf][nb] = __builtin_amdgcn_mfma_f32_16x16x32_bf16(aH[mf], bh, acc[mf][nb], 0, 0, 0);
                acc[mf][nb] = __builtin_amdgcn_mfma_f32_16x16x32_bf16(aH[mf], bl, acc[mf][nb], 0, 0, 0);
                acc[mf][nb] = __builtin_amdgcn_mfma_f32_16x16x32_bf16(aL[mf], bh, acc[mf][nb], 0, 0, 0);
            }
        }
        __syncthreads();
    }

    // ---- epilogue: C layout col = l&15, row = (l>>4)*4 + r ----
    float* obase = out + ((size_t)(b * LQ + q0)) * DV + w * 128;
#pragma unroll
    for (int mf = 0; mf < 2; ++mf)
#pragma unroll
        for (int nb = 0; nb < 8; ++nb)
#pragma unroll
            for (int r = 0; r < 4; ++r)
                obase[(size_t)(mf * 16 + (l >> 4) * 4 + r) * DV + nb * 16 + (l & 15)] = acc[mf][nb][r];
}

// ---------------------------------------------------------------------------
extern "C" void kernel_launch(void* const* d_in, const int* in_sizes, int n_in,
                              void* d_out, int out_size, void* d_ws, size_t ws_size,
                              hipStream_t stream) {
    const float* q    = (const float*)d_in[0];
    const float* k    = (const float*)d_in[1];
    const float* v    = (const float*)d_in[2];
    const int*   mask = (const int*)d_in[3];
    const float* w    = (const float*)d_in[4];

    float* out  = (float*)d_out;                       // [B, LQ, DV]
    float* attn = out + (size_t)BB * LQ * DV;          // [B, LQ, LK]
    float* ws   = (float*)d_ws;
    unsigned short* vH = (unsigned short*)(ws + WS_V16);
    unsigned short* vL = vH + (size_t)BB * DV * LK;

    qkw_kernel<<<4096, 256, 0, stream>>>(q, k, w, ws);
    vpack_kernel<<<dim3(32, 8, 4), 256, 0, stream>>>(v, vH, vL);
    rowstat_kernel<<<2048, 256, 0, stream>>>(mask, ws);
    pv_kernel<<<256, 256, 0, stream>>>(mask, ws, vH, vL, out, attn);
}

// Round 4
// 101.739 us; speedup vs baseline: 17.8137x; 2.2727x over previous
//
#include <hip/hip_runtime.h>
#include <math.h>

#define BB 4
#define LQ 2048
#define LK 2048
#define DK 512
#define DV 512

typedef __attribute__((ext_vector_type(8))) short bf16x8;
typedef __attribute__((ext_vector_type(4))) float f32x4;

// ws layout (f32-element offsets)
#define WS_QW    0                 // f32[8192]
#define WS_KW    8192              // f32[8192]
#define WS_M     16384             // f32[8192]
#define WS_INV   24576             // f32[8192]
#define WS_MPACK 32768             // u32[8192*64] = 2 MB
#define WS_V16   557056            // u16 vH[4194304], u16 vL[4194304] = 16.8 MB
#define WS_PART  4751360           // f32[2*4194304] = 33.6 MB
#define WS_NEEDED_SPLIT ((size_t)(WS_PART + 2 * 4194304) * 4)

__device__ inline void bsplit(float f, unsigned short& h, unsigned short& l) {
    unsigned int u  = __float_as_uint(f);
    unsigned int hu = u & 0xFFFF0000u;
    float rest = f - __uint_as_float(hu);
    h = (unsigned short)(u >> 16);
    l = (unsigned short)(__float_as_uint(rest) >> 16);
}

__device__ inline unsigned int packsplit(float f) {
    unsigned int u  = __float_as_uint(f);
    unsigned int hu = u & 0xFFFF0000u;
    float rest = f - __uint_as_float(hu);
    return hu | (__float_as_uint(rest) >> 16);
}

__device__ inline float bf2f(unsigned int u16v) {
    return __uint_as_float(u16v << 16);
}

// ---------------------------------------------------------------------------
// A: qw/kw — one wave per row.
// ---------------------------------------------------------------------------
__global__ __launch_bounds__(256) void qkw_kernel(const float* __restrict__ q,
                                                  const float* __restrict__ k,
                                                  const float* __restrict__ w,
                                                  float* __restrict__ ws) {
    int gw   = (int)((blockIdx.x * blockDim.x + threadIdx.x) >> 6);
    int lane = threadIdx.x & 63;
    const int nq = BB * LQ;
    const float* row = (gw < nq) ? (q + (size_t)gw * DK) : (k + (size_t)(gw - nq) * DK);

    float acc = 0.f;
#pragma unroll
    for (int j = 0; j < DK; j += 256) {
        int idx = j + lane * 4;
        float4 rv = *reinterpret_cast<const float4*>(row + idx);
        float4 wv = *reinterpret_cast<const float4*>(w + idx);
        acc += rv.x * wv.x + rv.y * wv.y + rv.z * wv.z + rv.w * wv.w;
    }
#pragma unroll
    for (int off = 32; off >= 1; off >>= 1) acc += __shfl_xor(acc, off, 64);
    if (lane == 0) ws[gw] = acc;
}

// ---------------------------------------------------------------------------
// C: v -> MFMA-fragment-ordered split bf16 (hi/lo).
// vFrag u16 index: (((b*32 + n16)*64 + k32)*64 + lane)*8 + j
//   element = vT[n16*16 + (lane&15)][k32*32 + (lane>>4)*8 + j]
// Block = (k32, b): 32 k-rows x 512 n.
// ---------------------------------------------------------------------------
__global__ __launch_bounds__(256) void vpack_kernel(const float* __restrict__ v,
                                                    unsigned short* __restrict__ vH,
                                                    unsigned short* __restrict__ vL) {
    __shared__ unsigned int tile[32][517];
    const int k32 = blockIdx.x;
    const int b   = blockIdx.y;
    const int k0  = k32 * 32;
    const int t   = threadIdx.x;

#pragma unroll
    for (int i = 0; i < 16; ++i) {
        int flat = i * 256 + t;          // 0..4095
        int row  = flat >> 7;            // 0..31
        int c4   = flat & 127;           // float4 col
        float4 f = *reinterpret_cast<const float4*>(
            v + ((size_t)(b * LK + k0 + row)) * DV + c4 * 4);
        tile[row][c4 * 4 + 0] = packsplit(f.x);
        tile[row][c4 * 4 + 1] = packsplit(f.y);
        tile[row][c4 * 4 + 2] = packsplit(f.z);
        tile[row][c4 * 4 + 3] = packsplit(f.w);
    }
    __syncthreads();

    const int w = t >> 6, l = t & 63;
    const int rbase = (l >> 4) * 8;
#pragma unroll
    for (int f = 0; f < 8; ++f) {
        int n16 = w * 8 + f;
        int col = n16 * 16 + (l & 15);
        unsigned int pk[8];
#pragma unroll
        for (int j = 0; j < 8; ++j) pk[j] = tile[rbase + j][col];
        uint4 hiw, low;
        hiw.x = (pk[0] >> 16) | (pk[1] & 0xFFFF0000u);
        hiw.y = (pk[2] >> 16) | (pk[3] & 0xFFFF0000u);
        hiw.z = (pk[4] >> 16) | (pk[5] & 0xFFFF0000u);
        hiw.w = (pk[6] >> 16) | (pk[7] & 0xFFFF0000u);
        low.x = (pk[0] & 0xFFFFu) | (pk[1] << 16);
        low.y = (pk[2] & 0xFFFFu) | (pk[3] << 16);
        low.z = (pk[4] & 0xFFFFu) | (pk[5] << 16);
        low.w = (pk[6] & 0xFFFFu) | (pk[7] << 16);
        size_t u16base = (((size_t)(b * 32 + n16)) * 64 + k32) * 512;
        *reinterpret_cast<uint4*>(vH + u16base + l * 8) = hiw;
        *reinterpret_cast<uint4*>(vL + u16base + l * 8) = low;
    }
}

// ---------------------------------------------------------------------------
// B1: per-row masked online softmax stats (m, 1/sum) + bit-packed mask.
// One wave per row.
// ---------------------------------------------------------------------------
__global__ __launch_bounds__(256) void rowstat_kernel(const int* __restrict__ mask,
                                                      float* __restrict__ ws,
                                                      unsigned int* __restrict__ mpack) {
    __shared__ float kws[LK];
    const int b = (blockIdx.x * 4) / LQ;
    const int t = threadIdx.x;

    const float4* kw4 = reinterpret_cast<const float4*>(ws + WS_KW + b * LK);
#pragma unroll
    for (int i = 0; i < 2; ++i)
        reinterpret_cast<float4*>(kws)[t + i * 256] = kw4[t + i * 256];
    __syncthreads();

    const int wave = t >> 6, lane = t & 63;
    const int rid  = blockIdx.x * 4 + wave;
    const float qwv = ws[WS_QW + rid];
    const int* mrow = mask + (size_t)rid * LK;

    float m = -INFINITY, s = 0.f;
#pragma unroll
    for (int i = 0; i < 8; ++i) {
        int e = (i * 64 + lane) * 4;
        int4  mi = *reinterpret_cast<const int4*>(mrow + e);
        float4 kv = reinterpret_cast<const float4*>(kws)[i * 64 + lane];
        float vals[4] = {kv.x, kv.y, kv.z, kv.w};
        int   msks[4] = {mi.x, mi.y, mi.z, mi.w};

        unsigned int bits = (msks[0] ? 1u : 0u) | (msks[1] ? 2u : 0u) |
                            (msks[2] ? 4u : 0u) | (msks[3] ? 8u : 0u);
        unsigned int wv = bits << ((lane & 7) * 4);
        wv |= __shfl_xor(wv, 1, 64);
        wv |= __shfl_xor(wv, 2, 64);
        wv |= __shfl_xor(wv, 4, 64);
        if ((lane & 7) == 0) mpack[(size_t)rid * 64 + i * 8 + (lane >> 3)] = wv;

#pragma unroll
        for (int j = 0; j < 4; ++j) {
            float sc = qwv - vals[j];
            sc = fmaxf(sc, 0.01f * sc);
            if (msks[j]) {
                if (sc > m) { s = s * __expf(m - sc) + 1.f; m = sc; }
                else        { s += __expf(sc - m); }
            }
        }
    }
#pragma unroll
    for (int off = 32; off >= 1; off >>= 1) {
        float mo = __shfl_xor(m, off, 64);
        float so = __shfl_xor(s, off, 64);
        float M  = fmaxf(m, mo);
        float sa = (m  == M) ? s  : s  * __expf(m  - M);
        float sb = (mo == M) ? so : so * __expf(mo - M);
        m = M; s = sa + sb;
    }
    if (lane == 0) {
        ws[WS_M   + rid] = m;
        ws[WS_INV + rid] = (s > 0.f) ? 1.f / s : 0.f;
    }
}

// ---------------------------------------------------------------------------
// B2: fused p-compute + attn write + split-bf16 MFMA PV.
// 512 thr (8 waves). Tile: 32 q-rows x 512 n, K split by nks.
// p stored in LDS in MFMA fragment order (byte 4*t on write => zero conflicts).
// ---------------------------------------------------------------------------
__global__ __launch_bounds__(512, 4) void pv_kernel(
        const unsigned int* __restrict__ mpack,
        const float* __restrict__ ws,
        const unsigned short* __restrict__ vH,
        const unsigned short* __restrict__ vL,
        float* __restrict__ attn,
        float* __restrict__ dst,
        int nks) {
    __shared__ float kw_lds[2048];
    __shared__ unsigned int pH32[512];
    __shared__ unsigned int pL32[512];

    const int bid = blockIdx.x;
    const int ks  = (nks == 2) ? (bid & 1) : 0;
    const int rst = (nks == 2) ? (bid >> 1) : bid;
    const int b   = rst & 3;
    const int qt  = rst >> 2;
    const int kspan  = LK / nks;
    const int ksteps = kspan >> 5;
    const int kbase  = ks * kspan;

    // FIX (R3 bug): each K-half writes its own partial buffer.
    float* dstk = dst + (size_t)ks * ((size_t)BB * LQ * DV);

    const int t = threadIdx.x;
    const int w = t >> 6, l = t & 63;

    // p-compute decode: thread t = (m<<8)|(l_pc<<2)|jp -> LDS u32 index t
    const int m_pc = t >> 8;
    const int l_pc = (t >> 2) & 63;
    const int jp   = t & 3;
    const int row_pc = m_pc * 16 + (l_pc & 15);
    const int kk_pc  = ((l_pc >> 4) << 3) + (jp << 1);   // even, 0..30
    const int rid_pc = b * LQ + qt * 32 + row_pc;

    // attn-write decode (raster order)
    const int row_at = t >> 4;             // 0..31
    const int kat    = (t & 15) << 1;      // 0..30
    const int idxA   = (row_at >> 4) * 256 +
                       (((kat >> 3) << 4) + (row_at & 15)) * 4 + ((kat & 7) >> 1);
    const int rid_at = b * LQ + qt * 32 + row_at;

    for (int i = t; i < kspan; i += 512)
        kw_lds[i] = ws[WS_KW + b * LK + kbase + i];
    const float qv = ws[WS_QW  + rid_pc];
    const float mv = ws[WS_M   + rid_pc];
    const float iv = ws[WS_INV + rid_pc];
    const unsigned int* mrow = mpack + (size_t)rid_pc * 64 + (kbase >> 5);
    float* arow = attn + (size_t)rid_at * LK + kbase;

    f32x4 acc[2][4];
#pragma unroll
    for (int mf = 0; mf < 2; ++mf)
#pragma unroll
        for (int nb = 0; nb < 4; ++nb)
            acc[mf][nb] = (f32x4){0.f, 0.f, 0.f, 0.f};
    __syncthreads();

    for (int s = 0; s < ksteps; ++s) {
        // ---- p-compute (fragment order) ----
        const unsigned int mw = mrow[s];
        const float kw0 = kw_lds[s * 32 + kk_pc];
        const float kw1 = kw_lds[s * 32 + kk_pc + 1];
        float sc0 = qv - kw0; sc0 = fmaxf(sc0, 0.01f * sc0);
        float sc1 = qv - kw1; sc1 = fmaxf(sc1, 0.01f * sc1);
        float p0 = ((mw >> kk_pc) & 1u)       ? __expf(sc0 - mv) * iv : 0.f;
        float p1 = ((mw >> (kk_pc + 1)) & 1u) ? __expf(sc1 - mv) * iv : 0.f;
        unsigned short h0, lo0, h1, lo1;
        bsplit(p0, h0, lo0); bsplit(p1, h1, lo1);
        pH32[t] = (unsigned int)h0  | ((unsigned int)h1  << 16);
        pL32[t] = (unsigned int)lo0 | ((unsigned int)lo1 << 16);
        __syncthreads();

        // ---- attn reconstruct + coalesced write ----
        {
            unsigned int hw = pH32[idxA], lw = pL32[idxA];
            float f0 = bf2f(hw & 0xFFFFu) + bf2f(lw & 0xFFFFu);
            float f1 = bf2f(hw >> 16)     + bf2f(lw >> 16);
            *reinterpret_cast<float2*>(arow + s * 32 + kat) = make_float2(f0, f1);
        }

        // ---- MFMA phase ----
        const bf16x8* pHf = reinterpret_cast<const bf16x8*>(pH32);
        const bf16x8* pLf = reinterpret_cast<const bf16x8*>(pL32);
        bf16x8 aH0 = pHf[l], aH1 = pHf[64 + l];
        bf16x8 aL0 = pLf[l], aL1 = pLf[64 + l];
        const int k32g = (kbase >> 5) + s;
#pragma unroll
        for (int nb = 0; nb < 4; ++nb) {
            size_t off = (((size_t)(b * 32 + w * 4 + nb)) * 64 + k32g) * 512 + l * 8;
            bf16x8 bh = *reinterpret_cast<const bf16x8*>(vH + off);
            bf16x8 bl = *reinterpret_cast<const bf16x8*>(vL + off);
            acc[0][nb] = __builtin_amdgcn_mfma_f32_16x16x32_bf16(aH0, bh, acc[0][nb], 0, 0, 0);
            acc[0][nb] = __builtin_amdgcn_mfma_f32_16x16x32_bf16(aH0, bl, acc[0][nb], 0, 0, 0);
            acc[0][nb] = __builtin_amdgcn_mfma_f32_16x16x32_bf16(aL0, bh, acc[0][nb], 0, 0, 0);
            acc[1][nb] = __builtin_amdgcn_mfma_f32_16x16x32_bf16(aH1, bh, acc[1][nb], 0, 0, 0);
            acc[1][nb] = __builtin_amdgcn_mfma_f32_16x16x32_bf16(aH1, bl, acc[1][nb], 0, 0, 0);
            acc[1][nb] = __builtin_amdgcn_mfma_f32_16x16x32_bf16(aL1, bh, acc[1][nb], 0, 0, 0);
        }
        __syncthreads();
    }

    // ---- epilogue: C layout col = l&15, row = mf*16 + (l>>4)*4 + r ----
    float* obase = dstk + ((size_t)(b * LQ + qt * 32)) * DV + w * 64 + (l & 15);
#pragma unroll
    for (int mf = 0; mf < 2; ++mf)
#pragma unroll
        for (int nb = 0; nb < 4; ++nb)
#pragma unroll
            for (int r = 0; r < 4; ++r)
                obase[(size_t)(mf * 16 + (l >> 4) * 4 + r) * DV + nb * 16] = acc[mf][nb][r];
}

// ---------------------------------------------------------------------------
// Reduce: out = part0 + part1 (float4).
// ---------------------------------------------------------------------------
__global__ __launch_bounds__(256) void reduce_kernel(const float* __restrict__ p0,
                                                     const float* __restrict__ p1,
                                                     float* __restrict__ out) {
    const int n4 = BB * LQ * DV / 4;   // 1048576
    int i = blockIdx.x * 256 + threadIdx.x;
    const float4* a = reinterpret_cast<const float4*>(p0);
    const float4* c = reinterpret_cast<const float4*>(p1);
    float4* o = reinterpret_cast<float4*>(out);
    for (; i < n4; i += 262144) {
        float4 x = a[i], y = c[i];
        o[i] = make_float4(x.x + y.x, x.y + y.y, x.z + y.z, x.w + y.w);
    }
}

// ---------------------------------------------------------------------------
extern "C" void kernel_launch(void* const* d_in, const int* in_sizes, int n_in,
                              void* d_out, int out_size, void* d_ws, size_t ws_size,
                              hipStream_t stream) {
    const float* q    = (const float*)d_in[0];
    const float* k    = (const float*)d_in[1];
    const float* v    = (const float*)d_in[2];
    const int*   mask = (const int*)d_in[3];
    const float* w    = (const float*)d_in[4];

    float* out  = (float*)d_out;                       // [B, LQ, DV]
    float* attn = out + (size_t)BB * LQ * DV;          // [B, LQ, LK]
    float* ws   = (float*)d_ws;

    unsigned int*   mpack = (unsigned int*)(ws + WS_MPACK);
    unsigned short* vH    = (unsigned short*)(ws + WS_V16);
    unsigned short* vL    = vH + (size_t)BB * DV * LK;
    float* part0 = ws + WS_PART;
    float* part1 = part0 + (size_t)BB * LQ * DV;

    const bool split = ws_size >= WS_NEEDED_SPLIT;

    qkw_kernel<<<4096, 256, 0, stream>>>(q, k, w, ws);
    vpack_kernel<<<dim3(64, 4), 256, 0, stream>>>(v, vH, vL);
    rowstat_kernel<<<2048, 256, 0, stream>>>(mask, ws, mpack);

    if (split) {
        pv_kernel<<<512, 512, 0, stream>>>(mpack, ws, vH, vL, attn, part0, 2);
        reduce_kernel<<<1024, 256, 0, stream>>>(part0, part1, out);
    } else {
        pv_kernel<<<256, 512, 0, stream>>>(mpack, ws, vH, vL, attn, out, 1);
    }
}

// Round 5
// 100.153 us; speedup vs baseline: 18.0959x; 1.0158x over previous
//
#include <hip/hip_runtime.h>
#include <math.h>

#define BB 4
#define LQ 2048
#define LK 2048
#define DK 512
#define DV 512

typedef __attribute__((ext_vector_type(8))) short bf16x8;
typedef __attribute__((ext_vector_type(4))) float f32x4;

// ws layout (f32-element offsets)
#define WS_QW    0                 // f32[8192]
#define WS_KW    8192              // f32[8192]
#define WS_M     16384             // f32[8192]
#define WS_INV   24576             // f32[8192]
#define WS_MPACK 32768             // u32[8192*64] = 2 MB
#define WS_V16   557056            // u16 vH[4194304], u16 vL[4194304] = 16.8 MB
#define WS_PART  4751360           // f32[2*4194304] = 33.6 MB
#define WS_NEEDED_SPLIT ((size_t)(WS_PART + 2 * 4194304) * 4)

__device__ inline void bsplit(float f, unsigned short& h, unsigned short& l) {
    unsigned int u  = __float_as_uint(f);
    unsigned int hu = u & 0xFFFF0000u;
    float rest = f - __uint_as_float(hu);
    h = (unsigned short)(u >> 16);
    l = (unsigned short)(__float_as_uint(rest) >> 16);
}

__device__ inline unsigned int packsplit(float f) {
    unsigned int u  = __float_as_uint(f);
    unsigned int hu = u & 0xFFFF0000u;
    float rest = f - __uint_as_float(hu);
    return hu | (__float_as_uint(rest) >> 16);
}

// ---------------------------------------------------------------------------
// A: qw/kw — one wave per row.
// ---------------------------------------------------------------------------
__global__ __launch_bounds__(256) void qkw_kernel(const float* __restrict__ q,
                                                  const float* __restrict__ k,
                                                  const float* __restrict__ w,
                                                  float* __restrict__ ws) {
    int gw   = (int)((blockIdx.x * blockDim.x + threadIdx.x) >> 6);
    int lane = threadIdx.x & 63;
    const int nq = BB * LQ;
    const float* row = (gw < nq) ? (q + (size_t)gw * DK) : (k + (size_t)(gw - nq) * DK);

    float acc = 0.f;
#pragma unroll
    for (int j = 0; j < DK; j += 256) {
        int idx = j + lane * 4;
        float4 rv = *reinterpret_cast<const float4*>(row + idx);
        float4 wv = *reinterpret_cast<const float4*>(w + idx);
        acc += rv.x * wv.x + rv.y * wv.y + rv.z * wv.z + rv.w * wv.w;
    }
#pragma unroll
    for (int off = 32; off >= 1; off >>= 1) acc += __shfl_xor(acc, off, 64);
    if (lane == 0) ws[gw] = acc;
}

// ---------------------------------------------------------------------------
// C: v -> MFMA-fragment-ordered split bf16 (hi/lo).
// vFrag u16 index: (((b*32 + n16)*64 + k32)*64 + lane)*8 + j
//   element = vT[n16*16 + (lane&15)][k32*32 + (lane>>4)*8 + j]
// ---------------------------------------------------------------------------
__global__ __launch_bounds__(256) void vpack_kernel(const float* __restrict__ v,
                                                    unsigned short* __restrict__ vH,
                                                    unsigned short* __restrict__ vL) {
    __shared__ unsigned int tile[32][517];
    const int k32 = blockIdx.x;
    const int b   = blockIdx.y;
    const int k0  = k32 * 32;
    const int t   = threadIdx.x;

#pragma unroll
    for (int i = 0; i < 16; ++i) {
        int flat = i * 256 + t;          // 0..4095
        int row  = flat >> 7;            // 0..31
        int c4   = flat & 127;           // float4 col
        float4 f = *reinterpret_cast<const float4*>(
            v + ((size_t)(b * LK + k0 + row)) * DV + c4 * 4);
        tile[row][c4 * 4 + 0] = packsplit(f.x);
        tile[row][c4 * 4 + 1] = packsplit(f.y);
        tile[row][c4 * 4 + 2] = packsplit(f.z);
        tile[row][c4 * 4 + 3] = packsplit(f.w);
    }
    __syncthreads();

    const int w = t >> 6, l = t & 63;
    const int rbase = (l >> 4) * 8;
#pragma unroll
    for (int f = 0; f < 8; ++f) {
        int n16 = w * 8 + f;
        int col = n16 * 16 + (l & 15);
        unsigned int pk[8];
#pragma unroll
        for (int j = 0; j < 8; ++j) pk[j] = tile[rbase + j][col];
        uint4 hiw, low;
        hiw.x = (pk[0] >> 16) | (pk[1] & 0xFFFF0000u);
        hiw.y = (pk[2] >> 16) | (pk[3] & 0xFFFF0000u);
        hiw.z = (pk[4] >> 16) | (pk[5] & 0xFFFF0000u);
        hiw.w = (pk[6] >> 16) | (pk[7] & 0xFFFF0000u);
        low.x = (pk[0] & 0xFFFFu) | (pk[1] << 16);
        low.y = (pk[2] & 0xFFFFu) | (pk[3] << 16);
        low.z = (pk[4] & 0xFFFFu) | (pk[5] << 16);
        low.w = (pk[6] & 0xFFFFu) | (pk[7] << 16);
        size_t u16base = (((size_t)(b * 32 + n16)) * 64 + k32) * 512;
        *reinterpret_cast<uint4*>(vH + u16base + l * 8) = hiw;
        *reinterpret_cast<uint4*>(vL + u16base + l * 8) = low;
    }
}

// ---------------------------------------------------------------------------
// B1: per-row masked online softmax stats (m, 1/sum) + bit-packed mask.
// ---------------------------------------------------------------------------
__global__ __launch_bounds__(256) void rowstat_kernel(const int* __restrict__ mask,
                                                      float* __restrict__ ws,
                                                      unsigned int* __restrict__ mpack) {
    __shared__ float kws[LK];
    const int b = (blockIdx.x * 4) / LQ;
    const int t = threadIdx.x;

    const float4* kw4 = reinterpret_cast<const float4*>(ws + WS_KW + b * LK);
#pragma unroll
    for (int i = 0; i < 2; ++i)
        reinterpret_cast<float4*>(kws)[t + i * 256] = kw4[t + i * 256];
    __syncthreads();

    const int wave = t >> 6, lane = t & 63;
    const int rid  = blockIdx.x * 4 + wave;
    const float qwv = ws[WS_QW + rid];
    const int* mrow = mask + (size_t)rid * LK;

    float m = -INFINITY, s = 0.f;
#pragma unroll
    for (int i = 0; i < 8; ++i) {
        int e = (i * 64 + lane) * 4;
        int4  mi = *reinterpret_cast<const int4*>(mrow + e);
        float4 kv = reinterpret_cast<const float4*>(kws)[i * 64 + lane];
        float vals[4] = {kv.x, kv.y, kv.z, kv.w};
        int   msks[4] = {mi.x, mi.y, mi.z, mi.w};

        unsigned int bits = (msks[0] ? 1u : 0u) | (msks[1] ? 2u : 0u) |
                            (msks[2] ? 4u : 0u) | (msks[3] ? 8u : 0u);
        unsigned int wv = bits << ((lane & 7) * 4);
        wv |= __shfl_xor(wv, 1, 64);
        wv |= __shfl_xor(wv, 2, 64);
        wv |= __shfl_xor(wv, 4, 64);
        if ((lane & 7) == 0) mpack[(size_t)rid * 64 + i * 8 + (lane >> 3)] = wv;

#pragma unroll
        for (int j = 0; j < 4; ++j) {
            float sc = qwv - vals[j];
            sc = fmaxf(sc, 0.01f * sc);
            if (msks[j]) {
                if (sc > m) { s = s * __expf(m - sc) + 1.f; m = sc; }
                else        { s += __expf(sc - m); }
            }
        }
    }
#pragma unroll
    for (int off = 32; off >= 1; off >>= 1) {
        float mo = __shfl_xor(m, off, 64);
        float so = __shfl_xor(s, off, 64);
        float M  = fmaxf(m, mo);
        float sa = (m  == M) ? s  : s  * __expf(m  - M);
        float sb = (mo == M) ? so : so * __expf(mo - M);
        m = M; s = sa + sb;
    }
    if (lane == 0) {
        ws[WS_M   + rid] = m;
        ws[WS_INV + rid] = (s > 0.f) ? 1.f / s : 0.f;
    }
}

// ---------------------------------------------------------------------------
// B2: fused p-compute + attn write + split-bf16 MFMA PV.
// M=64 q-tile, 512 thr (8 waves), wave = 64 q-rows x 64 n-cols.
// B-fragments software-pipelined (prefetch chunk s+1 during MFMA of s).
// attn written directly from p-compute registers (no LDS re-read).
// ---------------------------------------------------------------------------
__global__ __launch_bounds__(512, 2) void pv_kernel(
        const unsigned int* __restrict__ mpack,
        const float* __restrict__ ws,
        const unsigned short* __restrict__ vH,
        const unsigned short* __restrict__ vL,
        float* __restrict__ attn,
        float* __restrict__ dst,
        int nks) {
    __shared__ float kw_lds[2048];
    __shared__ unsigned int pH32[2048];
    __shared__ unsigned int pL32[2048];

    const int bid = blockIdx.x;
    const int ks  = (nks == 2) ? (bid & 1) : 0;
    const int rst = (nks == 2) ? (bid >> 1) : bid;
    const int b   = rst & 3;
    const int qt  = rst >> 2;              // 0..31
    const int kspan  = LK / nks;
    const int ksteps = kspan >> 5;
    const int kbase  = ks * kspan;
    float* dstk = dst + (size_t)ks * ((size_t)BB * LQ * DV);

    const int t = threadIdx.x;
    const int w = t >> 6, l = t & 63;

    // p-compute decode: thread t owns LDS u32 words t (rows 0..31) and t+512 (rows 32..63)
    const int m0   = t >> 8;               // 0..1
    const int lp   = (t >> 2) & 63;
    const int jp   = t & 3;
    const int row0 = m0 * 16 + (lp & 15);  // 0..31
    const int kk   = ((lp >> 4) << 3) + (jp << 1);   // even, 0..30
    const int rid0 = b * LQ + qt * 64 + row0;
    const int rid1 = rid0 + 32;

    const float qv0 = ws[WS_QW + rid0], mv0 = ws[WS_M + rid0], iv0 = ws[WS_INV + rid0];
    const float qv1 = ws[WS_QW + rid1], mv1 = ws[WS_M + rid1], iv1 = ws[WS_INV + rid1];
    const unsigned int* mrow0 = mpack + (size_t)rid0 * 64 + (kbase >> 5);
    const unsigned int* mrow1 = mpack + (size_t)rid1 * 64 + (kbase >> 5);
    float* arow0 = attn + (size_t)rid0 * LK + kbase + kk;
    float* arow1 = attn + (size_t)rid1 * LK + kbase + kk;

    // B fragment base offsets (u16 units) for chunk 0, per nb
    size_t nbase[4];
#pragma unroll
    for (int nb = 0; nb < 4; ++nb)
        nbase[nb] = (((size_t)(b * 32 + w * 4 + nb)) * 64 + (kbase >> 5)) * 512 + (size_t)l * 8;

    // prologue: load chunk-0 B-fragments; latency hides under kw staging + first p-compute
    bf16x8 bhC[4], blC[4], bhN[4], blN[4];
#pragma unroll
    for (int nb = 0; nb < 4; ++nb) {
        bhC[nb] = *reinterpret_cast<const bf16x8*>(vH + nbase[nb]);
        blC[nb] = *reinterpret_cast<const bf16x8*>(vL + nbase[nb]);
    }

    for (int i = t; i < kspan; i += 512)
        kw_lds[i] = ws[WS_KW + b * LK + kbase + i];

    f32x4 acc[4][4];
#pragma unroll
    for (int mf = 0; mf < 4; ++mf)
#pragma unroll
        for (int nb = 0; nb < 4; ++nb)
            acc[mf][nb] = (f32x4){0.f, 0.f, 0.f, 0.f};

    unsigned int mw0 = mrow0[0], mw1 = mrow1[0];
    unsigned int mw0N, mw1N;
    __syncthreads();

    for (int s = 0; s < ksteps; ++s) {
        // ---- phase 1: p-compute + direct attn write + fragment-order LDS store ----
        float2 kw2 = *reinterpret_cast<const float2*>(&kw_lds[s * 32 + kk]);
        float sc00 = qv0 - kw2.x; sc00 = fmaxf(sc00, 0.01f * sc00);
        float sc01 = qv0 - kw2.y; sc01 = fmaxf(sc01, 0.01f * sc01);
        float sc10 = qv1 - kw2.x; sc10 = fmaxf(sc10, 0.01f * sc10);
        float sc11 = qv1 - kw2.y; sc11 = fmaxf(sc11, 0.01f * sc11);
        float p00 = ((mw0 >> kk) & 1u)       ? __expf(sc00 - mv0) * iv0 : 0.f;
        float p01 = ((mw0 >> (kk + 1)) & 1u) ? __expf(sc01 - mv0) * iv0 : 0.f;
        float p10 = ((mw1 >> kk) & 1u)       ? __expf(sc10 - mv1) * iv1 : 0.f;
        float p11 = ((mw1 >> (kk + 1)) & 1u) ? __expf(sc11 - mv1) * iv1 : 0.f;
        *reinterpret_cast<float2*>(arow0 + s * 32) = make_float2(p00, p01);
        *reinterpret_cast<float2*>(arow1 + s * 32) = make_float2(p10, p11);
        unsigned short h00, l00, h01, l01, h10, l10, h11, l11;
        bsplit(p00, h00, l00); bsplit(p01, h01, l01);
        bsplit(p10, h10, l10); bsplit(p11, h11, l11);
        pH32[t]       = (unsigned int)h00 | ((unsigned int)h01 << 16);
        pL32[t]       = (unsigned int)l00 | ((unsigned int)l01 << 16);
        pH32[t + 512] = (unsigned int)h10 | ((unsigned int)h11 << 16);
        pL32[t + 512] = (unsigned int)l10 | ((unsigned int)l11 << 16);
        __syncthreads();

        // ---- phase 2: prefetch chunk s+1 B + mask, then A-reads + 48 MFMAs ----
        const int sn = (s + 1 < ksteps) ? s + 1 : s;
        mw0N = mrow0[sn]; mw1N = mrow1[sn];
#pragma unroll
        for (int nb = 0; nb < 4; ++nb) {
            bhN[nb] = *reinterpret_cast<const bf16x8*>(vH + nbase[nb] + (size_t)sn * 512);
            blN[nb] = *reinterpret_cast<const bf16x8*>(vL + nbase[nb] + (size_t)sn * 512);
        }

        const bf16x8* pHf = reinterpret_cast<const bf16x8*>(pH32);
        const bf16x8* pLf = reinterpret_cast<const bf16x8*>(pL32);
        bf16x8 aH[4], aL[4];
#pragma unroll
        for (int mf = 0; mf < 4; ++mf) {
            aH[mf] = pHf[mf * 64 + l];
            aL[mf] = pLf[mf * 64 + l];
        }
#pragma unroll
        for (int nb = 0; nb < 4; ++nb)
#pragma unroll
            for (int mf = 0; mf < 4; ++mf) {
                acc[mf][nb] = __builtin_amdgcn_mfma_f32_16x16x32_bf16(aH[mf], bhC[nb], acc[mf][nb], 0, 0, 0);
                acc[mf][nb] = __builtin_amdgcn_mfma_f32_16x16x32_bf16(aH[mf], blC[nb], acc[mf][nb], 0, 0, 0);
                acc[mf][nb] = __builtin_amdgcn_mfma_f32_16x16x32_bf16(aL[mf], bhC[nb], acc[mf][nb], 0, 0, 0);
            }
        __syncthreads();

#pragma unroll
        for (int nb = 0; nb < 4; ++nb) { bhC[nb] = bhN[nb]; blC[nb] = blN[nb]; }
        mw0 = mw0N; mw1 = mw1N;
    }

    // ---- epilogue: C layout col = l&15, row = mf*16 + (l>>4)*4 + r ----
    float* obase = dstk + ((size_t)(b * LQ + qt * 64)) * DV + w * 64 + (l & 15);
#pragma unroll
    for (int mf = 0; mf < 4; ++mf)
#pragma unroll
        for (int nb = 0; nb < 4; ++nb)
#pragma unroll
            for (int r = 0; r < 4; ++r)
                obase[(size_t)(mf * 16 + (l >> 4) * 4 + r) * DV + nb * 16] = acc[mf][nb][r];
}

// ---------------------------------------------------------------------------
// Reduce: out = part0 + part1 (float4).
// ---------------------------------------------------------------------------
__global__ __launch_bounds__(256) void reduce_kernel(const float* __restrict__ p0,
                                                     const float* __restrict__ p1,
                                                     float* __restrict__ out) {
    const int n4 = BB * LQ * DV / 4;   // 1048576
    int i = blockIdx.x * 256 + threadIdx.x;
    const float4* a = reinterpret_cast<const float4*>(p0);
    const float4* c = reinterpret_cast<const float4*>(p1);
    float4* o = reinterpret_cast<float4*>(out);
    for (; i < n4; i += 262144) {
        float4 x = a[i], y = c[i];
        o[i] = make_float4(x.x + y.x, x.y + y.y, x.z + y.z, x.w + y.w);
    }
}

// ---------------------------------------------------------------------------
extern "C" void kernel_launch(void* const* d_in, const int* in_sizes, int n_in,
                              void* d_out, int out_size, void* d_ws, size_t ws_size,
                              hipStream_t stream) {
    const float* q    = (const float*)d_in[0];
    const float* k    = (const float*)d_in[1];
    const float* v    = (const float*)d_in[2];
    const int*   mask = (const int*)d_in[3];
    const float* w    = (const float*)d_in[4];

    float* out  = (float*)d_out;                       // [B, LQ, DV]
    float* attn = out + (size_t)BB * LQ * DV;          // [B, LQ, LK]
    float* ws   = (float*)d_ws;

    unsigned int*   mpack = (unsigned int*)(ws + WS_MPACK);
    unsigned short* vH    = (unsigned short*)(ws + WS_V16);
    unsigned short* vL    = vH + (size_t)BB * DV * LK;
    float* part0 = ws + WS_PART;
    float* part1 = part0 + (size_t)BB * LQ * DV;

    const bool split = ws_size >= WS_NEEDED_SPLIT;

    qkw_kernel<<<4096, 256, 0, stream>>>(q, k, w, ws);
    vpack_kernel<<<dim3(64, 4), 256, 0, stream>>>(v, vH, vL);
    rowstat_kernel<<<2048, 256, 0, stream>>>(mask, ws, mpack);

    if (split) {
        // bid&7 = (ks, b) -> one (batch, k-half) v-slice per XCD (L2 locality)
        pv_kernel<<<256, 512, 0, stream>>>(mpack, ws, vH, vL, attn, part0, 2);
        reduce_kernel<<<1024, 256, 0, stream>>>(part0, part1, out);
    } else {
        pv_kernel<<<128, 512, 0, stream>>>(mpack, ws, vH, vL, attn, out, 1);
    }
}